// Round 2
// baseline (7867.968 us; speedup 1.0000x reference)
//
#include <hip/hip_runtime.h>
#include <math.h>

#define N0 200000
#define N1 50000
#define N2 10000
#define E0 750000
#define E1 150000
#define D 256
#define OUT 64
#define CAP 64

// ---------------------------------------------------------------------------
// Build per-target edge lists (capacity CAP per target; max degree ~38).
// ---------------------------------------------------------------------------
__global__ void fill_edges(const int* __restrict__ src, const int* __restrict__ dst,
                           int* __restrict__ cnt, int* __restrict__ eidx, int E) {
    int e = blockIdx.x * blockDim.x + threadIdx.x;
    if (e >= E) return;
    int d = dst[e];
    int pos = atomicAdd(&cnt[d], 1);
    if (pos < CAP) eidx[d * CAP + pos] = src[e];
}

// ---------------------------------------------------------------------------
// Mean-aggregate neighbor rows: one wave per target, 64 lanes x float4 = 256.
// ---------------------------------------------------------------------------
__global__ void aggregate(const float* __restrict__ X, const int* __restrict__ cnt,
                          const int* __restrict__ eidx, float* __restrict__ agg, int T) {
    int wave = threadIdx.x >> 6;
    int lane = threadIdx.x & 63;
    int t = blockIdx.x * 4 + wave;
    if (t >= T) return;
    int deg = cnt[t];
    int n = deg < CAP ? deg : CAP;
    const int* el = eidx + (size_t)t * CAP;
    float4 acc = {0.f, 0.f, 0.f, 0.f};
    for (int j = 0; j < n; ++j) {
        int s = el[j];
        const float4 v = *reinterpret_cast<const float4*>(X + (size_t)s * D + lane * 4);
        acc.x += v.x; acc.y += v.y; acc.z += v.z; acc.w += v.w;
    }
    float scale = deg > 0 ? 1.0f / (float)deg : 0.0f;
    acc.x *= scale; acc.y *= scale; acc.z *= scale; acc.w *= scale;
    *reinterpret_cast<float4*>(agg + (size_t)t * D + lane * 4) = acc;
}

// ---------------------------------------------------------------------------
// Fused dual GEMM: C[M][256] = act(A1@W1 + A2@W2 + b), K=N=256.
// 64x64 tile, BK=32, 256 threads, 4x4 micro-tile per thread.
// A staged transposed in LDS so inner loop reads are all b128.
// act: 0 = relu, 1 = tanh
// ---------------------------------------------------------------------------
__global__ void dual_gemm(const float* __restrict__ A1, const float* __restrict__ A2,
                          const float* __restrict__ W1, const float* __restrict__ W2,
                          const float* __restrict__ bias, float* __restrict__ C,
                          int M, int act) {
    __shared__ __align__(16) float sA1[32][68];
    __shared__ __align__(16) float sA2[32][68];
    __shared__ __align__(16) float sW1[32][68];
    __shared__ __align__(16) float sW2[32][68];

    const int tid = threadIdx.x;
    const int m0 = blockIdx.x * 64;
    const int n0 = blockIdx.y * 64;
    const int tr = tid >> 4;        // 0..15
    const int tc = tid & 15;        // 0..15

    const int arow = tid >> 3;          // 0..31
    const int ak = (tid & 7) * 4;       // 0..28
    const int wk = tid >> 4;            // 0..15
    const int wn = (tid & 15) * 4;      // 0..60

    float acc[4][4] = {};

    for (int k0 = 0; k0 < 256; k0 += 32) {
        // stage A tiles (transposed: sA[k][row]) -- two passes of 32 rows
        #pragma unroll
        for (int p = 0; p < 2; ++p) {
            int row = p * 32 + arow;
            int m = m0 + row;
            float4 v1 = {0.f,0.f,0.f,0.f}, v2 = {0.f,0.f,0.f,0.f};
            if (m < M) {
                v1 = *reinterpret_cast<const float4*>(A1 + (size_t)m * D + k0 + ak);
                v2 = *reinterpret_cast<const float4*>(A2 + (size_t)m * D + k0 + ak);
            }
            sA1[ak + 0][row] = v1.x; sA1[ak + 1][row] = v1.y;
            sA1[ak + 2][row] = v1.z; sA1[ak + 3][row] = v1.w;
            sA2[ak + 0][row] = v2.x; sA2[ak + 1][row] = v2.y;
            sA2[ak + 2][row] = v2.z; sA2[ak + 3][row] = v2.w;
        }
        // stage W tiles (natural: sW[k][n]) -- two passes of 16 k-rows
        #pragma unroll
        for (int p = 0; p < 2; ++p) {
            int k = k0 + p * 16 + wk;
            *reinterpret_cast<float4*>(&sW1[p * 16 + wk][wn]) =
                *reinterpret_cast<const float4*>(W1 + (size_t)k * D + n0 + wn);
            *reinterpret_cast<float4*>(&sW2[p * 16 + wk][wn]) =
                *reinterpret_cast<const float4*>(W2 + (size_t)k * D + n0 + wn);
        }
        __syncthreads();

        #pragma unroll
        for (int k = 0; k < 32; ++k) {
            float4 a1 = *reinterpret_cast<const float4*>(&sA1[k][tr * 4]);
            float4 a2 = *reinterpret_cast<const float4*>(&sA2[k][tr * 4]);
            float4 w1 = *reinterpret_cast<const float4*>(&sW1[k][tc * 4]);
            float4 w2 = *reinterpret_cast<const float4*>(&sW2[k][tc * 4]);
            #define FMA_ROW(r, a1c, a2c) \
                acc[r][0] += a1c * w1.x + a2c * w2.x; \
                acc[r][1] += a1c * w1.y + a2c * w2.y; \
                acc[r][2] += a1c * w1.z + a2c * w2.z; \
                acc[r][3] += a1c * w1.w + a2c * w2.w;
            FMA_ROW(0, a1.x, a2.x)
            FMA_ROW(1, a1.y, a2.y)
            FMA_ROW(2, a1.z, a2.z)
            FMA_ROW(3, a1.w, a2.w)
            #undef FMA_ROW
        }
        __syncthreads();
    }

    float4 bv = *reinterpret_cast<const float4*>(bias + n0 + tc * 4);
    #pragma unroll
    for (int i = 0; i < 4; ++i) {
        int m = m0 + tr * 4 + i;
        if (m < M) {
            float4 o;
            o.x = acc[i][0] + bv.x;
            o.y = acc[i][1] + bv.y;
            o.z = acc[i][2] + bv.z;
            o.w = acc[i][3] + bv.w;
            if (act == 0) {
                o.x = fmaxf(o.x, 0.f); o.y = fmaxf(o.y, 0.f);
                o.z = fmaxf(o.z, 0.f); o.w = fmaxf(o.w, 0.f);
            } else {
                o.x = tanhf(o.x); o.y = tanhf(o.y);
                o.z = tanhf(o.z); o.w = tanhf(o.w);
            }
            *reinterpret_cast<float4*>(C + (size_t)m * D + n0 + tc * 4) = o;
        }
    }
}

// ---------------------------------------------------------------------------
// Final: out[M][64] = softmax(H @ Wlin + blin). Wlin staged in LDS.
// One wave per row; lane = output column.
// ---------------------------------------------------------------------------
__global__ void final_softmax(const float* __restrict__ H, const float* __restrict__ Wlin,
                              const float* __restrict__ blin, float* __restrict__ out,
                              int M, int rows_per_block) {
    __shared__ __align__(16) float sW[D * OUT];
    __shared__ float sb[OUT];
    for (int i = threadIdx.x * 4; i < D * OUT; i += 1024) {
        *reinterpret_cast<float4*>(&sW[i]) = *reinterpret_cast<const float4*>(&Wlin[i]);
    }
    if (threadIdx.x < OUT) sb[threadIdx.x] = blin[threadIdx.x];
    __syncthreads();

    int wave = threadIdx.x >> 6;
    int lane = threadIdx.x & 63;
    int base = blockIdx.x * rows_per_block;
    int end = base + rows_per_block;
    if (end > M) end = M;

    for (int r = base + wave; r < end; r += 4) {
        float4 h = *reinterpret_cast<const float4*>(H + (size_t)r * D + lane * 4);
        float acc = sb[lane];
        #pragma unroll
        for (int kq = 0; kq < 64; ++kq) {
            float hx = __shfl(h.x, kq);
            float hy = __shfl(h.y, kq);
            float hz = __shfl(h.z, kq);
            float hw = __shfl(h.w, kq);
            acc += hx * sW[(4 * kq + 0) * OUT + lane];
            acc += hy * sW[(4 * kq + 1) * OUT + lane];
            acc += hz * sW[(4 * kq + 2) * OUT + lane];
            acc += hw * sW[(4 * kq + 3) * OUT + lane];
        }
        // softmax across 64 lanes
        float mx = acc;
        #pragma unroll
        for (int off = 32; off > 0; off >>= 1) mx = fmaxf(mx, __shfl_xor(mx, off));
        float e = __expf(acc - mx);
        float s = e;
        #pragma unroll
        for (int off = 32; off > 0; off >>= 1) s += __shfl_xor(s, off);
        out[(size_t)r * OUT + lane] = e / s;
    }
}

extern "C" void kernel_launch(void* const* d_in, const int* in_sizes, int n_in,
                              void* d_out, int out_size, void* d_ws, size_t ws_size,
                              hipStream_t stream) {
    const float* x    = (const float*)d_in[0];
    const int*   src0 = (const int*)d_in[1];
    const int*   dst0 = (const int*)d_in[2];
    const int*   src1 = (const int*)d_in[3];
    const int*   dst1 = (const int*)d_in[4];
    const float* Wl0  = (const float*)d_in[5];
    const float* bl0  = (const float*)d_in[6];
    const float* Wr0  = (const float*)d_in[7];
    const float* Wl1  = (const float*)d_in[8];
    const float* bl1  = (const float*)d_in[9];
    const float* Wr1  = (const float*)d_in[10];
    const float* Wlin = (const float*)d_in[11];
    const float* blin = (const float*)d_in[12];

    char* ws = (char*)d_ws;
    size_t off = 0;
    auto alloc = [&](size_t bytes) {
        void* p = ws + off;
        off += (bytes + 255) & ~(size_t)255;
        return p;
    };
    int*   cnt0  = (int*)alloc((size_t)N1 * 4);
    int*   eidx0 = (int*)alloc((size_t)N1 * CAP * 4);
    int*   cnt1  = (int*)alloc((size_t)N2 * 4);
    int*   eidx1 = (int*)alloc((size_t)N2 * CAP * 4);
    float* agg0  = (float*)alloc((size_t)N1 * D * 4);
    float* h0    = (float*)alloc((size_t)N1 * D * 4);
    float* agg1  = (float*)alloc((size_t)N2 * D * 4);
    float* h1    = (float*)alloc((size_t)N2 * D * 4);

    hipMemsetAsync(cnt0, 0, (size_t)N1 * 4, stream);
    hipMemsetAsync(cnt1, 0, (size_t)N2 * 4, stream);

    fill_edges<<<(E0 + 255) / 256, 256, 0, stream>>>(src0, dst0, cnt0, eidx0, E0);
    aggregate<<<(N1 + 3) / 4, 256, 0, stream>>>(x, cnt0, eidx0, agg0, N1);
    dual_gemm<<<dim3((N1 + 63) / 64, 4), 256, 0, stream>>>(agg0, x, Wl0, Wr0, bl0, h0, N1, 0);

    fill_edges<<<(E1 + 255) / 256, 256, 0, stream>>>(src1, dst1, cnt1, eidx1, E1);
    aggregate<<<(N2 + 3) / 4, 256, 0, stream>>>(h0, cnt1, eidx1, agg1, N2);
    dual_gemm<<<dim3((N2 + 63) / 64, 4), 256, 0, stream>>>(agg1, h0, Wl1, Wr1, bl1, h1, N2, 1);

    final_softmax<<<250, 256, 0, stream>>>(h1, Wlin, blin, (float*)d_out, N2, 40);
}

// Round 3
// 780.199 us; speedup vs baseline: 10.0846x; 10.0846x over previous
//
#include <hip/hip_runtime.h>
#include <math.h>

#define N0 200000
#define N1 50000
#define N2 10000
#define E0 750000
#define E1 150000
#define D 256
#define OUT 64
#define CAP 64

// ---------------------------------------------------------------------------
// Build per-target edge lists (capacity CAP per target; max degree ~38).
// ---------------------------------------------------------------------------
__global__ void fill_edges(const int* __restrict__ src, const int* __restrict__ dst,
                           int* __restrict__ cnt, int* __restrict__ eidx, int E) {
    int e = blockIdx.x * blockDim.x + threadIdx.x;
    if (e >= E) return;
    int d = dst[e];
    int pos = atomicAdd(&cnt[d], 1);
    if (pos < CAP) eidx[d * CAP + pos] = src[e];
}

// ---------------------------------------------------------------------------
// Mean-aggregate neighbor rows: one wave per target, 64 lanes x float4 = 256.
// ---------------------------------------------------------------------------
__global__ void aggregate(const float* __restrict__ X, const int* __restrict__ cnt,
                          const int* __restrict__ eidx, float* __restrict__ agg, int T) {
    int wave = threadIdx.x >> 6;
    int lane = threadIdx.x & 63;
    int t = blockIdx.x * 4 + wave;
    if (t >= T) return;
    int deg = cnt[t];
    int n = deg < CAP ? deg : CAP;
    const int* el = eidx + (size_t)t * CAP;
    float4 acc = {0.f, 0.f, 0.f, 0.f};
    for (int j = 0; j < n; ++j) {
        int s = el[j];
        const float4 v = *reinterpret_cast<const float4*>(X + (size_t)s * D + lane * 4);
        acc.x += v.x; acc.y += v.y; acc.z += v.z; acc.w += v.w;
    }
    float scale = deg > 0 ? 1.0f / (float)deg : 0.0f;
    acc.x *= scale; acc.y *= scale; acc.z *= scale; acc.w *= scale;
    *reinterpret_cast<float4*>(agg + (size_t)t * D + lane * 4) = acc;
}

// ---------------------------------------------------------------------------
// Fused dual GEMM: C[M][256] = act(A1@W1 + A2@W2 + b), K=N=256.
// 64x64 tile, BK=32, 256 threads, 4x4 micro-tile per thread.
// __launch_bounds__(256,2): allow up to 256 VGPR/wave. Round-2 counters showed
// the default allocation capped at 64 VGPR and spilled the accumulators
// (24 GB of scratch HBM traffic, VALUBusy 3%).
// act: 0 = relu, 1 = tanh
// ---------------------------------------------------------------------------
__global__ void __launch_bounds__(256, 2)
dual_gemm(const float* __restrict__ A1, const float* __restrict__ A2,
          const float* __restrict__ W1, const float* __restrict__ W2,
          const float* __restrict__ bias, float* __restrict__ C,
          int M, int act) {
    __shared__ __align__(16) float sA1[32][68];
    __shared__ __align__(16) float sA2[32][68];
    __shared__ __align__(16) float sW1[32][68];
    __shared__ __align__(16) float sW2[32][68];

    const int tid = threadIdx.x;
    const int m0 = blockIdx.x * 64;
    const int n0 = blockIdx.y * 64;
    const int tr = tid >> 4;        // 0..15
    const int tc = tid & 15;        // 0..15

    const int arow = tid >> 3;          // 0..31
    const int ak = (tid & 7) * 4;       // 0..28
    const int wk = tid >> 4;            // 0..15
    const int wn = (tid & 15) * 4;      // 0..60

    float acc[4][4] = {};

    for (int k0 = 0; k0 < 256; k0 += 32) {
        // stage A tiles (transposed: sA[k][row]) -- two passes of 32 rows
        #pragma unroll
        for (int p = 0; p < 2; ++p) {
            int row = p * 32 + arow;
            int m = m0 + row;
            float4 v1 = {0.f,0.f,0.f,0.f}, v2 = {0.f,0.f,0.f,0.f};
            if (m < M) {
                v1 = *reinterpret_cast<const float4*>(A1 + (size_t)m * D + k0 + ak);
                v2 = *reinterpret_cast<const float4*>(A2 + (size_t)m * D + k0 + ak);
            }
            sA1[ak + 0][row] = v1.x; sA1[ak + 1][row] = v1.y;
            sA1[ak + 2][row] = v1.z; sA1[ak + 3][row] = v1.w;
            sA2[ak + 0][row] = v2.x; sA2[ak + 1][row] = v2.y;
            sA2[ak + 2][row] = v2.z; sA2[ak + 3][row] = v2.w;
        }
        // stage W tiles (natural: sW[k][n]) -- two passes of 16 k-rows
        #pragma unroll
        for (int p = 0; p < 2; ++p) {
            int k = k0 + p * 16 + wk;
            *reinterpret_cast<float4*>(&sW1[p * 16 + wk][wn]) =
                *reinterpret_cast<const float4*>(W1 + (size_t)k * D + n0 + wn);
            *reinterpret_cast<float4*>(&sW2[p * 16 + wk][wn]) =
                *reinterpret_cast<const float4*>(W2 + (size_t)k * D + n0 + wn);
        }
        __syncthreads();

        #pragma unroll
        for (int k = 0; k < 32; ++k) {
            float4 a1 = *reinterpret_cast<const float4*>(&sA1[k][tr * 4]);
            float4 a2 = *reinterpret_cast<const float4*>(&sA2[k][tr * 4]);
            float4 w1 = *reinterpret_cast<const float4*>(&sW1[k][tc * 4]);
            float4 w2 = *reinterpret_cast<const float4*>(&sW2[k][tc * 4]);
            #define FMA_ROW(r, a1c, a2c) \
                acc[r][0] += a1c * w1.x + a2c * w2.x; \
                acc[r][1] += a1c * w1.y + a2c * w2.y; \
                acc[r][2] += a1c * w1.z + a2c * w2.z; \
                acc[r][3] += a1c * w1.w + a2c * w2.w;
            FMA_ROW(0, a1.x, a2.x)
            FMA_ROW(1, a1.y, a2.y)
            FMA_ROW(2, a1.z, a2.z)
            FMA_ROW(3, a1.w, a2.w)
            #undef FMA_ROW
        }
        __syncthreads();
    }

    float4 bv = *reinterpret_cast<const float4*>(bias + n0 + tc * 4);
    #pragma unroll
    for (int i = 0; i < 4; ++i) {
        int m = m0 + tr * 4 + i;
        if (m < M) {
            float4 o;
            o.x = acc[i][0] + bv.x;
            o.y = acc[i][1] + bv.y;
            o.z = acc[i][2] + bv.z;
            o.w = acc[i][3] + bv.w;
            if (act == 0) {
                o.x = fmaxf(o.x, 0.f); o.y = fmaxf(o.y, 0.f);
                o.z = fmaxf(o.z, 0.f); o.w = fmaxf(o.w, 0.f);
            } else {
                o.x = tanhf(o.x); o.y = tanhf(o.y);
                o.z = tanhf(o.z); o.w = tanhf(o.w);
            }
            *reinterpret_cast<float4*>(C + (size_t)m * D + n0 + tc * 4) = o;
        }
    }
}

// ---------------------------------------------------------------------------
// Final: out[M][64] = softmax(H @ Wlin + blin). Wlin staged in LDS.
// One wave per row; lane = output column.
// ---------------------------------------------------------------------------
__global__ void final_softmax(const float* __restrict__ H, const float* __restrict__ Wlin,
                              const float* __restrict__ blin, float* __restrict__ out,
                              int M, int rows_per_block) {
    __shared__ __align__(16) float sW[D * OUT];
    __shared__ float sb[OUT];
    for (int i = threadIdx.x * 4; i < D * OUT; i += 1024) {
        *reinterpret_cast<float4*>(&sW[i]) = *reinterpret_cast<const float4*>(&Wlin[i]);
    }
    if (threadIdx.x < OUT) sb[threadIdx.x] = blin[threadIdx.x];
    __syncthreads();

    int wave = threadIdx.x >> 6;
    int lane = threadIdx.x & 63;
    int base = blockIdx.x * rows_per_block;
    int end = base + rows_per_block;
    if (end > M) end = M;

    for (int r = base + wave; r < end; r += 4) {
        float4 h = *reinterpret_cast<const float4*>(H + (size_t)r * D + lane * 4);
        float acc = sb[lane];
        #pragma unroll
        for (int kq = 0; kq < 64; ++kq) {
            float hx = __shfl(h.x, kq);
            float hy = __shfl(h.y, kq);
            float hz = __shfl(h.z, kq);
            float hw = __shfl(h.w, kq);
            acc += hx * sW[(4 * kq + 0) * OUT + lane];
            acc += hy * sW[(4 * kq + 1) * OUT + lane];
            acc += hz * sW[(4 * kq + 2) * OUT + lane];
            acc += hw * sW[(4 * kq + 3) * OUT + lane];
        }
        // softmax across 64 lanes
        float mx = acc;
        #pragma unroll
        for (int off = 32; off > 0; off >>= 1) mx = fmaxf(mx, __shfl_xor(mx, off));
        float e = __expf(acc - mx);
        float s = e;
        #pragma unroll
        for (int off = 32; off > 0; off >>= 1) s += __shfl_xor(s, off);
        out[(size_t)r * OUT + lane] = e / s;
    }
}

extern "C" void kernel_launch(void* const* d_in, const int* in_sizes, int n_in,
                              void* d_out, int out_size, void* d_ws, size_t ws_size,
                              hipStream_t stream) {
    const float* x    = (const float*)d_in[0];
    const int*   src0 = (const int*)d_in[1];
    const int*   dst0 = (const int*)d_in[2];
    const int*   src1 = (const int*)d_in[3];
    const int*   dst1 = (const int*)d_in[4];
    const float* Wl0  = (const float*)d_in[5];
    const float* bl0  = (const float*)d_in[6];
    const float* Wr0  = (const float*)d_in[7];
    const float* Wl1  = (const float*)d_in[8];
    const float* bl1  = (const float*)d_in[9];
    const float* Wr1  = (const float*)d_in[10];
    const float* Wlin = (const float*)d_in[11];
    const float* blin = (const float*)d_in[12];

    char* ws = (char*)d_ws;
    size_t off = 0;
    auto alloc = [&](size_t bytes) {
        void* p = ws + off;
        off += (bytes + 255) & ~(size_t)255;
        return p;
    };
    int*   cnt0  = (int*)alloc((size_t)N1 * 4);
    int*   eidx0 = (int*)alloc((size_t)N1 * CAP * 4);
    int*   cnt1  = (int*)alloc((size_t)N2 * 4);
    int*   eidx1 = (int*)alloc((size_t)N2 * CAP * 4);
    float* agg0  = (float*)alloc((size_t)N1 * D * 4);
    float* h0    = (float*)alloc((size_t)N1 * D * 4);
    float* agg1  = (float*)alloc((size_t)N2 * D * 4);
    float* h1    = (float*)alloc((size_t)N2 * D * 4);

    hipMemsetAsync(cnt0, 0, (size_t)N1 * 4, stream);
    hipMemsetAsync(cnt1, 0, (size_t)N2 * 4, stream);

    fill_edges<<<(E0 + 255) / 256, 256, 0, stream>>>(src0, dst0, cnt0, eidx0, E0);
    aggregate<<<(N1 + 3) / 4, 256, 0, stream>>>(x, cnt0, eidx0, agg0, N1);
    dual_gemm<<<dim3((N1 + 63) / 64, 4), 256, 0, stream>>>(agg0, x, Wl0, Wr0, bl0, h0, N1, 0);

    fill_edges<<<(E1 + 255) / 256, 256, 0, stream>>>(src1, dst1, cnt1, eidx1, E1);
    aggregate<<<(N2 + 3) / 4, 256, 0, stream>>>(h0, cnt1, eidx1, agg1, N2);
    dual_gemm<<<dim3((N2 + 63) / 64, 4), 256, 0, stream>>>(agg1, h0, Wl1, Wr1, bl1, h1, N2, 1);

    final_softmax<<<250, 256, 0, stream>>>(h1, Wlin, blin, (float*)d_out, N2, 40);
}

// Round 4
// 631.684 us; speedup vs baseline: 12.4555x; 1.2351x over previous
//
#include <hip/hip_runtime.h>
#include <math.h>

#define N0 200000
#define N1 50000
#define N2 10000
#define E0 750000
#define E1 150000
#define D 256
#define OUT 64
#define CAP 64

#define BM 128
#define BN 128
#define BKK 64

typedef unsigned int uint32;
using short8 = __attribute__((ext_vector_type(8))) short;
using f32x4 = __attribute__((ext_vector_type(4))) float;

// ---- bf16 split helpers: value v ~ bf16(hi) + bf16(lo), packed (hi<<16)|lo ----
__device__ __forceinline__ unsigned short bf16_rne(float f) {
    unsigned int u = __float_as_uint(f);
    unsigned int r = (u + 0x7FFFu + ((u >> 16) & 1u)) >> 16;
    return (unsigned short)r;
}
__device__ __forceinline__ float bf16_f32(unsigned short h) {
    return __uint_as_float(((unsigned int)h) << 16);
}
__device__ __forceinline__ uint32 pack2(float v) {
    unsigned short hi = bf16_rne(v);
    unsigned short lo = bf16_rne(v - bf16_f32(hi));
    return (((uint32)hi) << 16) | (uint32)lo;
}
__device__ __forceinline__ float unpack_f32(uint32 u) {
    return __uint_as_float(u & 0xFFFF0000u) + __uint_as_float(u << 16);
}

// ---------------------------------------------------------------------------
// Build per-target edge lists (capacity CAP per target; max degree ~38).
// ---------------------------------------------------------------------------
__global__ void fill_edges(const int* __restrict__ src, const int* __restrict__ dst,
                           int* __restrict__ cnt, int* __restrict__ eidx, int E) {
    int e = blockIdx.x * blockDim.x + threadIdx.x;
    if (e >= E) return;
    int d = dst[e];
    int pos = atomicAdd(&cnt[d], 1);
    if (pos < CAP) eidx[d * CAP + pos] = src[e];
}

// ---------------------------------------------------------------------------
// Mean-aggregate neighbor rows; output packed hi/lo bf16 (u32 per element).
// SRCPACKED=false: src is fp32 [n][256]; true: src is packed u32 [n][256].
// One wave per target, 64 lanes x 4 elems = 256.
// ---------------------------------------------------------------------------
template<bool SRCPACKED>
__global__ void aggregate_p(const void* __restrict__ src, const int* __restrict__ cnt,
                            const int* __restrict__ eidx, uint32* __restrict__ aggp, int T) {
    int wave = threadIdx.x >> 6;
    int lane = threadIdx.x & 63;
    int t = blockIdx.x * 4 + wave;
    if (t >= T) return;
    int deg = cnt[t];
    int n = deg < CAP ? deg : CAP;
    const int* el = eidx + (size_t)t * CAP;
    float a0 = 0.f, a1 = 0.f, a2 = 0.f, a3 = 0.f;
    for (int j = 0; j < n; ++j) {
        int s = el[j];
        if constexpr (SRCPACKED) {
            uint4 u = *reinterpret_cast<const uint4*>((const uint32*)src + (size_t)s * D + lane * 4);
            a0 += unpack_f32(u.x); a1 += unpack_f32(u.y);
            a2 += unpack_f32(u.z); a3 += unpack_f32(u.w);
        } else {
            float4 v = *reinterpret_cast<const float4*>((const float*)src + (size_t)s * D + lane * 4);
            a0 += v.x; a1 += v.y; a2 += v.z; a3 += v.w;
        }
    }
    float sc = deg > 0 ? 1.0f / (float)deg : 0.0f;
    uint4 o;
    o.x = pack2(a0 * sc); o.y = pack2(a1 * sc);
    o.z = pack2(a2 * sc); o.w = pack2(a3 * sc);
    *reinterpret_cast<uint4*>(aggp + (size_t)t * D + lane * 4) = o;
}

// ---------------------------------------------------------------------------
// Pack W into transposed split form: WTp[n][kc] (kc<256 -> Wl[kc][n], else Wr).
// grid 256 blocks (n), 512 threads (kc).
// ---------------------------------------------------------------------------
__global__ void pack_wt(const float* __restrict__ Wl, const float* __restrict__ Wr,
                        uint32* __restrict__ WTp) {
    int n = blockIdx.x;
    int kc = threadIdx.x;
    float v = (kc < 256) ? Wl[(size_t)kc * D + n] : Wr[(size_t)(kc - 256) * D + n];
    WTp[(size_t)n * 512 + kc] = pack2(v);
}

// ---------------------------------------------------------------------------
// Split-bf16 MFMA GEMM: C[M][256] = act([A1|A2] @ Wcat + bias), K=512.
// 3-term Markidis split per product: hi*hi + hi*lo + lo*hi (fp32 accum).
// 128x128 tile, BK=64, 4 waves (2x2), 4x4 x (16x16x32) fragments per wave.
// LDS XOR-swizzle (byte ^= (row&7)<<4) for conflict-free ds_read_b128.
// ACT 0: relu, store packed u32. ACT 1: tanh, store fp32.
// ---------------------------------------------------------------------------
template<int ACT, bool A2PACKED>
__global__ void __launch_bounds__(256, 2)
gemm_split(const uint32* __restrict__ A1p, const uint32* __restrict__ A2p,
           const float* __restrict__ A2f, const uint32* __restrict__ WTp,
           const float* __restrict__ bias, uint32* __restrict__ Cp,
           float* __restrict__ Cf, int M) {
    __shared__ char sAhi[BM * BKK * 2];
    __shared__ char sAlo[BM * BKK * 2];
    __shared__ char sBhi[BN * BKK * 2];
    __shared__ char sBlo[BN * BKK * 2];

    const int tid = threadIdx.x;
    const int m0 = blockIdx.x * BM;
    const int n0 = blockIdx.y * BN;
    const int wid = tid >> 6, lane = tid & 63;
    const int wm = wid >> 1, wn = wid & 1;
    const int lr = lane & 15;
    const int lk2 = (lane >> 4) * 16;   // byte offset of this lane's k-slice

    f32x4 acc[4][4];
    #pragma unroll
    for (int i = 0; i < 4; ++i)
        #pragma unroll
        for (int j = 0; j < 4; ++j)
            acc[i][j] = (f32x4){0.f, 0.f, 0.f, 0.f};

    for (int k0 = 0; k0 < 512; k0 += BKK) {
        if (k0) __syncthreads();
        // ---- stage A tile: 128 rows x 64 k (source u32/f32), hi/lo bf16 to LDS ----
        #pragma unroll
        for (int it = 0; it < 8; ++it) {
            int flat = it * 1024 + tid * 4;
            int row = flat >> 6;
            int kq = flat & 63;
            int m = m0 + row;
            unsigned short h0, h1, h2, h3, l0, l1, l2, l3;
            if (k0 < 256) {
                uint4 u = make_uint4(0u, 0u, 0u, 0u);
                if (m < M) u = *reinterpret_cast<const uint4*>(A1p + (size_t)m * D + k0 + kq);
                h0 = u.x >> 16; l0 = u.x & 0xffff;
                h1 = u.y >> 16; l1 = u.y & 0xffff;
                h2 = u.z >> 16; l2 = u.z & 0xffff;
                h3 = u.w >> 16; l3 = u.w & 0xffff;
            } else if constexpr (A2PACKED) {
                uint4 u = make_uint4(0u, 0u, 0u, 0u);
                if (m < M) u = *reinterpret_cast<const uint4*>(A2p + (size_t)m * D + (k0 - 256) + kq);
                h0 = u.x >> 16; l0 = u.x & 0xffff;
                h1 = u.y >> 16; l1 = u.y & 0xffff;
                h2 = u.z >> 16; l2 = u.z & 0xffff;
                h3 = u.w >> 16; l3 = u.w & 0xffff;
            } else {
                float4 f = make_float4(0.f, 0.f, 0.f, 0.f);
                if (m < M) f = *reinterpret_cast<const float4*>(A2f + (size_t)m * D + (k0 - 256) + kq);
                h0 = bf16_rne(f.x); l0 = bf16_rne(f.x - bf16_f32(h0));
                h1 = bf16_rne(f.y); l1 = bf16_rne(f.y - bf16_f32(h1));
                h2 = bf16_rne(f.z); l2 = bf16_rne(f.z - bf16_f32(h2));
                h3 = bf16_rne(f.w); l3 = bf16_rne(f.w - bf16_f32(h3));
            }
            int ba = row * (BKK * 2) + ((kq * 2) ^ ((row & 7) << 4));
            *reinterpret_cast<ushort4*>(sAhi + ba) = make_ushort4(h0, h1, h2, h3);
            *reinterpret_cast<ushort4*>(sAlo + ba) = make_ushort4(l0, l1, l2, l3);
        }
        // ---- stage B tile: 128 n-rows x 64 k from WTp (always packed) ----
        #pragma unroll
        for (int it = 0; it < 8; ++it) {
            int flat = it * 1024 + tid * 4;
            int row = flat >> 6;
            int kq = flat & 63;
            uint4 u = *reinterpret_cast<const uint4*>(WTp + (size_t)(n0 + row) * 512 + k0 + kq);
            int bb = row * (BKK * 2) + ((kq * 2) ^ ((row & 7) << 4));
            *reinterpret_cast<ushort4*>(sBhi + bb) =
                make_ushort4(u.x >> 16, u.y >> 16, u.z >> 16, u.w >> 16);
            *reinterpret_cast<ushort4*>(sBlo + bb) =
                make_ushort4(u.x & 0xffff, u.y & 0xffff, u.z & 0xffff, u.w & 0xffff);
        }
        __syncthreads();
        // ---- compute: 2 kk-slabs of K=32 ----
        #pragma unroll
        for (int kk2 = 0; kk2 < BKK * 2; kk2 += 64) {
            short8 ah[4], al[4], bh[4], bl[4];
            #pragma unroll
            for (int f = 0; f < 4; ++f) {
                int ra = wm * 64 + f * 16 + lr;
                int oa = ra * (BKK * 2) + (((kk2 + lk2)) ^ ((ra & 7) << 4));
                ah[f] = *reinterpret_cast<const short8*>(sAhi + oa);
                al[f] = *reinterpret_cast<const short8*>(sAlo + oa);
                int rb = wn * 64 + f * 16 + lr;
                int ob = rb * (BKK * 2) + (((kk2 + lk2)) ^ ((rb & 7) << 4));
                bh[f] = *reinterpret_cast<const short8*>(sBhi + ob);
                bl[f] = *reinterpret_cast<const short8*>(sBlo + ob);
            }
            #pragma unroll
            for (int i = 0; i < 4; ++i)
                #pragma unroll
                for (int j = 0; j < 4; ++j) {
                    acc[i][j] = __builtin_amdgcn_mfma_f32_16x16x32_bf16(ah[i], bh[j], acc[i][j], 0, 0, 0);
                    acc[i][j] = __builtin_amdgcn_mfma_f32_16x16x32_bf16(ah[i], bl[j], acc[i][j], 0, 0, 0);
                    acc[i][j] = __builtin_amdgcn_mfma_f32_16x16x32_bf16(al[i], bh[j], acc[i][j], 0, 0, 0);
                }
        }
    }
    // ---- epilogue: D[row][col], col = lane&15, row = (lane>>4)*4 + reg ----
    #pragma unroll
    for (int fn = 0; fn < 4; ++fn) {
        int col = n0 + wn * 64 + fn * 16 + lr;
        float bv = bias[col];
        #pragma unroll
        for (int fm = 0; fm < 4; ++fm) {
            int rbase = m0 + wm * 64 + fm * 16 + (lane >> 4) * 4;
            #pragma unroll
            for (int r = 0; r < 4; ++r) {
                int m = rbase + r;
                if (m < M) {
                    float v = acc[fm][fn][r] + bv;
                    if (ACT == 0) {
                        v = fmaxf(v, 0.f);
                        Cp[(size_t)m * D + col] = pack2(v);
                    } else {
                        Cf[(size_t)m * D + col] = tanhf(v);
                    }
                }
            }
        }
    }
}

// ---------------------------------------------------------------------------
// Final: out[M][64] = softmax(H @ Wlin + blin). Wlin staged in LDS.
// One wave per row; lane = output column.
// ---------------------------------------------------------------------------
__global__ void final_softmax(const float* __restrict__ H, const float* __restrict__ Wlin,
                              const float* __restrict__ blin, float* __restrict__ out,
                              int M, int rows_per_block) {
    __shared__ __align__(16) float sW[D * OUT];
    __shared__ float sb[OUT];
    for (int i = threadIdx.x * 4; i < D * OUT; i += 1024) {
        *reinterpret_cast<float4*>(&sW[i]) = *reinterpret_cast<const float4*>(&Wlin[i]);
    }
    if (threadIdx.x < OUT) sb[threadIdx.x] = blin[threadIdx.x];
    __syncthreads();

    int wave = threadIdx.x >> 6;
    int lane = threadIdx.x & 63;
    int base = blockIdx.x * rows_per_block;
    int end = base + rows_per_block;
    if (end > M) end = M;

    for (int r = base + wave; r < end; r += 4) {
        float4 h = *reinterpret_cast<const float4*>(H + (size_t)r * D + lane * 4);
        float acc = sb[lane];
        #pragma unroll
        for (int kq = 0; kq < 64; ++kq) {
            float hx = __shfl(h.x, kq);
            float hy = __shfl(h.y, kq);
            float hz = __shfl(h.z, kq);
            float hw = __shfl(h.w, kq);
            acc += hx * sW[(4 * kq + 0) * OUT + lane];
            acc += hy * sW[(4 * kq + 1) * OUT + lane];
            acc += hz * sW[(4 * kq + 2) * OUT + lane];
            acc += hw * sW[(4 * kq + 3) * OUT + lane];
        }
        float mx = acc;
        #pragma unroll
        for (int off = 32; off > 0; off >>= 1) mx = fmaxf(mx, __shfl_xor(mx, off));
        float e = __expf(acc - mx);
        float s = e;
        #pragma unroll
        for (int off = 32; off > 0; off >>= 1) s += __shfl_xor(s, off);
        out[(size_t)r * OUT + lane] = e / s;
    }
}

extern "C" void kernel_launch(void* const* d_in, const int* in_sizes, int n_in,
                              void* d_out, int out_size, void* d_ws, size_t ws_size,
                              hipStream_t stream) {
    const float* x    = (const float*)d_in[0];
    const int*   src0 = (const int*)d_in[1];
    const int*   dst0 = (const int*)d_in[2];
    const int*   src1 = (const int*)d_in[3];
    const int*   dst1 = (const int*)d_in[4];
    const float* Wl0  = (const float*)d_in[5];
    const float* bl0  = (const float*)d_in[6];
    const float* Wr0  = (const float*)d_in[7];
    const float* Wl1  = (const float*)d_in[8];
    const float* bl1  = (const float*)d_in[9];
    const float* Wr1  = (const float*)d_in[10];
    const float* Wlin = (const float*)d_in[11];
    const float* blin = (const float*)d_in[12];

    char* ws = (char*)d_ws;
    size_t off = 0;
    auto alloc = [&](size_t bytes) {
        void* p = ws + off;
        off += (bytes + 255) & ~(size_t)255;
        return p;
    };
    int*    cnt0  = (int*)alloc((size_t)N1 * 4);
    int*    eidx0 = (int*)alloc((size_t)N1 * CAP * 4);
    int*    cnt1  = (int*)alloc((size_t)N2 * 4);
    int*    eidx1 = (int*)alloc((size_t)N2 * CAP * 4);
    uint32* agg0p = (uint32*)alloc((size_t)N1 * D * 4);
    uint32* h0p   = (uint32*)alloc((size_t)N1 * D * 4);
    uint32* agg1p = (uint32*)alloc((size_t)N2 * D * 4);
    float*  h1f   = (float*)alloc((size_t)N2 * D * 4);
    uint32* WTp0  = (uint32*)alloc((size_t)D * 512 * 4);
    uint32* WTp1  = (uint32*)alloc((size_t)D * 512 * 4);

    hipMemsetAsync(cnt0, 0, (size_t)N1 * 4, stream);
    hipMemsetAsync(cnt1, 0, (size_t)N2 * 4, stream);

    pack_wt<<<256, 512, 0, stream>>>(Wl0, Wr0, WTp0);
    pack_wt<<<256, 512, 0, stream>>>(Wl1, Wr1, WTp1);

    fill_edges<<<(E0 + 255) / 256, 256, 0, stream>>>(src0, dst0, cnt0, eidx0, E0);
    aggregate_p<false><<<(N1 + 3) / 4, 256, 0, stream>>>(x, cnt0, eidx0, agg0p, N1);
    gemm_split<0, false><<<dim3((N1 + BM - 1) / BM, 2), 256, 0, stream>>>(
        agg0p, (const uint32*)nullptr, x, WTp0, bl0, h0p, (float*)nullptr, N1);

    fill_edges<<<(E1 + 255) / 256, 256, 0, stream>>>(src1, dst1, cnt1, eidx1, E1);
    aggregate_p<true><<<(N2 + 3) / 4, 256, 0, stream>>>(h0p, cnt1, eidx1, agg1p, N2);
    gemm_split<1, true><<<dim3((N2 + BM - 1) / BM, 2), 256, 0, stream>>>(
        agg1p, h0p, (const float*)nullptr, WTp1, bl1, (uint32*)nullptr, h1f, N2);

    final_softmax<<<250, 256, 0, stream>>>(h1f, Wlin, blin, (float*)d_out, N2, 40);
}

// Round 5
// 411.745 us; speedup vs baseline: 19.1088x; 1.5342x over previous
//
#include <hip/hip_runtime.h>
#include <math.h>

#define N0 200000
#define N1 50000
#define N2 10000
#define E0 750000
#define E1 150000
#define D 256
#define OUT 64
#define CAP 64

#define BM 128
#define BN 128
#define BKK 64

typedef unsigned int uint32;
using short8 = __attribute__((ext_vector_type(8))) short;
using f32x4 = __attribute__((ext_vector_type(4))) float;

// ---- bf16 split helpers: value v ~ bf16(hi) + bf16(lo), packed (hi<<16)|lo ----
__device__ __forceinline__ unsigned short bf16_rne(float f) {
    unsigned int u = __float_as_uint(f);
    unsigned int r = (u + 0x7FFFu + ((u >> 16) & 1u)) >> 16;
    return (unsigned short)r;
}
__device__ __forceinline__ float bf16_f32(unsigned short h) {
    return __uint_as_float(((unsigned int)h) << 16);
}
__device__ __forceinline__ uint32 pack2(float v) {
    unsigned short hi = bf16_rne(v);
    unsigned short lo = bf16_rne(v - bf16_f32(hi));
    return (((uint32)hi) << 16) | (uint32)lo;
}
__device__ __forceinline__ float unpack_f32(uint32 u) {
    return __uint_as_float(u & 0xFFFF0000u) + __uint_as_float(u << 16);
}

// ---------------------------------------------------------------------------
// Build per-target edge lists (capacity CAP per target; max degree ~38).
// ---------------------------------------------------------------------------
__global__ void fill_edges(const int* __restrict__ src, const int* __restrict__ dst,
                           int* __restrict__ cnt, int* __restrict__ eidx, int E) {
    int e = blockIdx.x * blockDim.x + threadIdx.x;
    if (e >= E) return;
    int d = dst[e];
    int pos = atomicAdd(&cnt[d], 1);
    if (pos < CAP) eidx[d * CAP + pos] = src[e];
}

// ---------------------------------------------------------------------------
// Mean-aggregate neighbor rows; output packed hi/lo bf16 (u32 per element).
// SRCPACKED=false: src is fp32 [n][256]; true: src is packed u32 [n][256].
// One wave per target, 64 lanes x 4 elems = 256.
// ---------------------------------------------------------------------------
template<bool SRCPACKED>
__global__ void aggregate_p(const void* __restrict__ src, const int* __restrict__ cnt,
                            const int* __restrict__ eidx, uint32* __restrict__ aggp, int T) {
    int wave = threadIdx.x >> 6;
    int lane = threadIdx.x & 63;
    int t = blockIdx.x * 4 + wave;
    if (t >= T) return;
    int deg = cnt[t];
    int n = deg < CAP ? deg : CAP;
    const int* el = eidx + (size_t)t * CAP;
    float a0 = 0.f, a1 = 0.f, a2 = 0.f, a3 = 0.f;
    for (int j = 0; j < n; ++j) {
        int s = el[j];
        if constexpr (SRCPACKED) {
            uint4 u = *reinterpret_cast<const uint4*>((const uint32*)src + (size_t)s * D + lane * 4);
            a0 += unpack_f32(u.x); a1 += unpack_f32(u.y);
            a2 += unpack_f32(u.z); a3 += unpack_f32(u.w);
        } else {
            float4 v = *reinterpret_cast<const float4*>((const float*)src + (size_t)s * D + lane * 4);
            a0 += v.x; a1 += v.y; a2 += v.z; a3 += v.w;
        }
    }
    float sc = deg > 0 ? 1.0f / (float)deg : 0.0f;
    uint4 o;
    o.x = pack2(a0 * sc); o.y = pack2(a1 * sc);
    o.z = pack2(a2 * sc); o.w = pack2(a3 * sc);
    *reinterpret_cast<uint4*>(aggp + (size_t)t * D + lane * 4) = o;
}

// ---------------------------------------------------------------------------
// Pack W into transposed split form: WTp[n][kc] (kc<256 -> Wl[kc][n], else Wr).
// grid 256 blocks (n), 512 threads (kc).
// ---------------------------------------------------------------------------
__global__ void pack_wt(const float* __restrict__ Wl, const float* __restrict__ Wr,
                        uint32* __restrict__ WTp) {
    int n = blockIdx.x;
    int kc = threadIdx.x;
    float v = (kc < 256) ? Wl[(size_t)kc * D + n] : Wr[(size_t)(kc - 256) * D + n];
    WTp[(size_t)n * 512 + kc] = pack2(v);
}

// ---------------------------------------------------------------------------
// Split-bf16 MFMA GEMM: C[M][256] = act([A1|A2] @ Wcat + bias), K=512.
// 3-term Markidis split per product: hi*hi + hi*lo + lo*hi (fp32 accum).
// 128x128 tile, BK=64, 4 waves (2x2), 4x4 x (16x16x32) fragments per wave.
// LDS XOR-swizzle (byte ^= (row&7)<<4) for conflict-free ds_read_b128.
// ACT 0: relu, store packed u32. ACT 1: tanh, store fp32.
// ---------------------------------------------------------------------------
template<int ACT, bool A2PACKED>
__global__ void __launch_bounds__(256, 2)
gemm_split(const uint32* __restrict__ A1p, const uint32* __restrict__ A2p,
           const float* __restrict__ A2f, const uint32* __restrict__ WTp,
           const float* __restrict__ bias, uint32* __restrict__ Cp,
           float* __restrict__ Cf, int M) {
    __shared__ char sAhi[BM * BKK * 2];
    __shared__ char sAlo[BM * BKK * 2];
    __shared__ char sBhi[BN * BKK * 2];
    __shared__ char sBlo[BN * BKK * 2];

    const int tid = threadIdx.x;
    const int m0 = blockIdx.x * BM;
    const int n0 = blockIdx.y * BN;
    const int wid = tid >> 6, lane = tid & 63;
    const int wm = wid >> 1, wn = wid & 1;
    const int lr = lane & 15;
    const int lk2 = (lane >> 4) * 16;   // byte offset of this lane's k-slice

    f32x4 acc[4][4];
    #pragma unroll
    for (int i = 0; i < 4; ++i)
        #pragma unroll
        for (int j = 0; j < 4; ++j)
            acc[i][j] = (f32x4){0.f, 0.f, 0.f, 0.f};

    for (int k0 = 0; k0 < 512; k0 += BKK) {
        if (k0) __syncthreads();
        // ---- stage A tile: 128 rows x 64 k (source u32/f32), hi/lo bf16 to LDS ----
        #pragma unroll
        for (int it = 0; it < 8; ++it) {
            int flat = it * 1024 + tid * 4;
            int row = flat >> 6;
            int kq = flat & 63;
            int m = m0 + row;
            unsigned short h0, h1, h2, h3, l0, l1, l2, l3;
            if (k0 < 256) {
                uint4 u = make_uint4(0u, 0u, 0u, 0u);
                if (m < M) u = *reinterpret_cast<const uint4*>(A1p + (size_t)m * D + k0 + kq);
                h0 = u.x >> 16; l0 = u.x & 0xffff;
                h1 = u.y >> 16; l1 = u.y & 0xffff;
                h2 = u.z >> 16; l2 = u.z & 0xffff;
                h3 = u.w >> 16; l3 = u.w & 0xffff;
            } else if constexpr (A2PACKED) {
                uint4 u = make_uint4(0u, 0u, 0u, 0u);
                if (m < M) u = *reinterpret_cast<const uint4*>(A2p + (size_t)m * D + (k0 - 256) + kq);
                h0 = u.x >> 16; l0 = u.x & 0xffff;
                h1 = u.y >> 16; l1 = u.y & 0xffff;
                h2 = u.z >> 16; l2 = u.z & 0xffff;
                h3 = u.w >> 16; l3 = u.w & 0xffff;
            } else {
                float4 f = make_float4(0.f, 0.f, 0.f, 0.f);
                if (m < M) f = *reinterpret_cast<const float4*>(A2f + (size_t)m * D + (k0 - 256) + kq);
                h0 = bf16_rne(f.x); l0 = bf16_rne(f.x - bf16_f32(h0));
                h1 = bf16_rne(f.y); l1 = bf16_rne(f.y - bf16_f32(h1));
                h2 = bf16_rne(f.z); l2 = bf16_rne(f.z - bf16_f32(h2));
                h3 = bf16_rne(f.w); l3 = bf16_rne(f.w - bf16_f32(h3));
            }
            int ba = row * (BKK * 2) + ((kq * 2) ^ ((row & 7) << 4));
            *reinterpret_cast<ushort4*>(sAhi + ba) = make_ushort4(h0, h1, h2, h3);
            *reinterpret_cast<ushort4*>(sAlo + ba) = make_ushort4(l0, l1, l2, l3);
        }
        // ---- stage B tile: 128 n-rows x 64 k from WTp (always packed) ----
        #pragma unroll
        for (int it = 0; it < 8; ++it) {
            int flat = it * 1024 + tid * 4;
            int row = flat >> 6;
            int kq = flat & 63;
            uint4 u = *reinterpret_cast<const uint4*>(WTp + (size_t)(n0 + row) * 512 + k0 + kq);
            int bb = row * (BKK * 2) + ((kq * 2) ^ ((row & 7) << 4));
            *reinterpret_cast<ushort4*>(sBhi + bb) =
                make_ushort4(u.x >> 16, u.y >> 16, u.z >> 16, u.w >> 16);
            *reinterpret_cast<ushort4*>(sBlo + bb) =
                make_ushort4(u.x & 0xffff, u.y & 0xffff, u.z & 0xffff, u.w & 0xffff);
        }
        __syncthreads();
        // ---- compute: 2 kk-slabs of K=32 ----
        #pragma unroll
        for (int kk2 = 0; kk2 < BKK * 2; kk2 += 64) {
            short8 ah[4], al[4], bh[4], bl[4];
            #pragma unroll
            for (int f = 0; f < 4; ++f) {
                int ra = wm * 64 + f * 16 + lr;
                int oa = ra * (BKK * 2) + (((kk2 + lk2)) ^ ((ra & 7) << 4));
                ah[f] = *reinterpret_cast<const short8*>(sAhi + oa);
                al[f] = *reinterpret_cast<const short8*>(sAlo + oa);
                int rb = wn * 64 + f * 16 + lr;
                int ob = rb * (BKK * 2) + (((kk2 + lk2)) ^ ((rb & 7) << 4));
                bh[f] = *reinterpret_cast<const short8*>(sBhi + ob);
                bl[f] = *reinterpret_cast<const short8*>(sBlo + ob);
            }
            #pragma unroll
            for (int i = 0; i < 4; ++i)
                #pragma unroll
                for (int j = 0; j < 4; ++j) {
                    acc[i][j] = __builtin_amdgcn_mfma_f32_16x16x32_bf16(ah[i], bh[j], acc[i][j], 0, 0, 0);
                    acc[i][j] = __builtin_amdgcn_mfma_f32_16x16x32_bf16(ah[i], bl[j], acc[i][j], 0, 0, 0);
                    acc[i][j] = __builtin_amdgcn_mfma_f32_16x16x32_bf16(al[i], bh[j], acc[i][j], 0, 0, 0);
                }
        }
    }
    // ---- epilogue: D[row][col], col = lane&15, row = (lane>>4)*4 + reg ----
    #pragma unroll
    for (int fn = 0; fn < 4; ++fn) {
        int col = n0 + wn * 64 + fn * 16 + lr;
        float bv = bias[col];
        #pragma unroll
        for (int fm = 0; fm < 4; ++fm) {
            int rbase = m0 + wm * 64 + fm * 16 + (lane >> 4) * 4;
            #pragma unroll
            for (int r = 0; r < 4; ++r) {
                int m = rbase + r;
                if (m < M) {
                    float v = acc[fm][fn][r] + bv;
                    if (ACT == 0) {
                        v = fmaxf(v, 0.f);
                        Cp[(size_t)m * D + col] = pack2(v);
                    } else {
                        Cf[(size_t)m * D + col] = tanhf(v);
                    }
                }
            }
        }
    }
}

// ---------------------------------------------------------------------------
// Final: out[M][64] = softmax(H @ Wlin + blin).
// One wave per row, NO LDS: Wlin (64 KB) is L2-resident; direct global reads.
// Round-4 counters: the LDS-staging version ran 250 fat blocks -> 1 wave/SIMD,
// Occupancy 10.8%, VALUBusy 2.3%, 252 us. This version: 2500 blocks, 40 waves/CU.
// ---------------------------------------------------------------------------
__global__ void final_softmax(const float* __restrict__ H, const float* __restrict__ Wlin,
                              const float* __restrict__ blin, float* __restrict__ out,
                              int M) {
    int wave = threadIdx.x >> 6;
    int lane = threadIdx.x & 63;
    int r = blockIdx.x * 4 + wave;
    if (r >= M) return;

    float4 h = *reinterpret_cast<const float4*>(H + (size_t)r * D + lane * 4);
    float acc = blin[lane];
    #pragma unroll 8
    for (int kq = 0; kq < 64; ++kq) {
        float hx = __shfl(h.x, kq);
        float hy = __shfl(h.y, kq);
        float hz = __shfl(h.z, kq);
        float hw = __shfl(h.w, kq);
        acc += hx * Wlin[(4 * kq + 0) * OUT + lane];
        acc += hy * Wlin[(4 * kq + 1) * OUT + lane];
        acc += hz * Wlin[(4 * kq + 2) * OUT + lane];
        acc += hw * Wlin[(4 * kq + 3) * OUT + lane];
    }
    float mx = acc;
    #pragma unroll
    for (int off = 32; off > 0; off >>= 1) mx = fmaxf(mx, __shfl_xor(mx, off));
    float e = __expf(acc - mx);
    float s = e;
    #pragma unroll
    for (int off = 32; off > 0; off >>= 1) s += __shfl_xor(s, off);
    out[(size_t)r * OUT + lane] = e / s;
}

extern "C" void kernel_launch(void* const* d_in, const int* in_sizes, int n_in,
                              void* d_out, int out_size, void* d_ws, size_t ws_size,
                              hipStream_t stream) {
    const float* x    = (const float*)d_in[0];
    const int*   src0 = (const int*)d_in[1];
    const int*   dst0 = (const int*)d_in[2];
    const int*   src1 = (const int*)d_in[3];
    const int*   dst1 = (const int*)d_in[4];
    const float* Wl0  = (const float*)d_in[5];
    const float* bl0  = (const float*)d_in[6];
    const float* Wr0  = (const float*)d_in[7];
    const float* Wl1  = (const float*)d_in[8];
    const float* bl1  = (const float*)d_in[9];
    const float* Wr1  = (const float*)d_in[10];
    const float* Wlin = (const float*)d_in[11];
    const float* blin = (const float*)d_in[12];

    char* ws = (char*)d_ws;
    size_t off = 0;
    auto alloc = [&](size_t bytes) {
        void* p = ws + off;
        off += (bytes + 255) & ~(size_t)255;
        return p;
    };
    int*    cnt0  = (int*)alloc((size_t)N1 * 4);
    int*    eidx0 = (int*)alloc((size_t)N1 * CAP * 4);
    int*    cnt1  = (int*)alloc((size_t)N2 * 4);
    int*    eidx1 = (int*)alloc((size_t)N2 * CAP * 4);
    uint32* agg0p = (uint32*)alloc((size_t)N1 * D * 4);
    uint32* h0p   = (uint32*)alloc((size_t)N1 * D * 4);
    uint32* agg1p = (uint32*)alloc((size_t)N2 * D * 4);
    float*  h1f   = (float*)alloc((size_t)N2 * D * 4);
    uint32* WTp0  = (uint32*)alloc((size_t)D * 512 * 4);
    uint32* WTp1  = (uint32*)alloc((size_t)D * 512 * 4);

    hipMemsetAsync(cnt0, 0, (size_t)N1 * 4, stream);
    hipMemsetAsync(cnt1, 0, (size_t)N2 * 4, stream);

    pack_wt<<<256, 512, 0, stream>>>(Wl0, Wr0, WTp0);
    pack_wt<<<256, 512, 0, stream>>>(Wl1, Wr1, WTp1);

    fill_edges<<<(E0 + 255) / 256, 256, 0, stream>>>(src0, dst0, cnt0, eidx0, E0);
    aggregate_p<false><<<(N1 + 3) / 4, 256, 0, stream>>>(x, cnt0, eidx0, agg0p, N1);
    gemm_split<0, false><<<dim3((N1 + BM - 1) / BM, 2), 256, 0, stream>>>(
        agg0p, (const uint32*)nullptr, x, WTp0, bl0, h0p, (float*)nullptr, N1);

    fill_edges<<<(E1 + 255) / 256, 256, 0, stream>>>(src1, dst1, cnt1, eidx1, E1);
    aggregate_p<true><<<(N2 + 3) / 4, 256, 0, stream>>>(h0p, cnt1, eidx1, agg1p, N2);
    gemm_split<1, true><<<dim3((N2 + BM - 1) / BM, 2), 256, 0, stream>>>(
        agg1p, h0p, (const float*)nullptr, WTp1, bl1, (uint32*)nullptr, h1f, N2);

    final_softmax<<<(N2 + 3) / 4, 256, 0, stream>>>(h1f, Wlin, blin, (float*)d_out, N2);
}

// Round 7
// 402.669 us; speedup vs baseline: 19.5395x; 1.0225x over previous
//
#include <hip/hip_runtime.h>
#include <math.h>

#define N0 200000
#define N1 50000
#define N2 10000
#define E0 750000
#define E1 150000
#define D 256
#define OUT 64
#define CAP 64

#define BM 128
#define BN 128
#define BKK 64

typedef unsigned int uint32;
using short8 = __attribute__((ext_vector_type(8))) short;
using f32x4 = __attribute__((ext_vector_type(4))) float;

// ---- bf16 split helpers: value v ~ bf16(hi) + bf16(lo), packed (hi<<16)|lo ----
__device__ __forceinline__ unsigned short bf16_rne(float f) {
    unsigned int u = __float_as_uint(f);
    unsigned int r = (u + 0x7FFFu + ((u >> 16) & 1u)) >> 16;
    return (unsigned short)r;
}
__device__ __forceinline__ float bf16_f32(unsigned short h) {
    return __uint_as_float(((unsigned int)h) << 16);
}
__device__ __forceinline__ uint32 pack2(float v) {
    unsigned short hi = bf16_rne(v);
    unsigned short lo = bf16_rne(v - bf16_f32(hi));
    return (((uint32)hi) << 16) | (uint32)lo;
}
__device__ __forceinline__ float unpack_f32(uint32 u) {
    return __uint_as_float(u & 0xFFFF0000u) + __uint_as_float(u << 16);
}

// ---------------------------------------------------------------------------
// Build per-target edge lists (capacity CAP per target; max degree ~38).
// ---------------------------------------------------------------------------
__global__ void fill_edges(const int* __restrict__ src, const int* __restrict__ dst,
                           int* __restrict__ cnt, int* __restrict__ eidx, int E) {
    int e = blockIdx.x * blockDim.x + threadIdx.x;
    if (e >= E) return;
    int d = dst[e];
    int pos = atomicAdd(&cnt[d], 1);
    if (pos < CAP) eidx[d * CAP + pos] = src[e];
}

// ---------------------------------------------------------------------------
// Mean-aggregate neighbor rows; output packed hi/lo bf16 (u32 per element).
// SRCPACKED=false: src is fp32 [n][256]; true: src is packed u32 [n][256].
// One wave per target, 64 lanes x 4 elems = 256.
// Round-5 counters: VGPR=12 -> ~1 outstanding load/wave, latency-bound at
// 4.9 TB/s effective gather. Unroll x4 (int4 index load + 4 independent row
// loads in flight) to raise memory-level parallelism.
// ---------------------------------------------------------------------------
template<bool SRCPACKED>
__global__ void aggregate_p(const void* __restrict__ src, const int* __restrict__ cnt,
                            const int* __restrict__ eidx, uint32* __restrict__ aggp, int T) {
    int wave = threadIdx.x >> 6;
    int lane = threadIdx.x & 63;
    int t = blockIdx.x * 4 + wave;
    if (t >= T) return;
    int deg = cnt[t];
    int n = deg < CAP ? deg : CAP;
    const int* el = eidx + (size_t)t * CAP;
    float a0 = 0.f, a1 = 0.f, a2 = 0.f, a3 = 0.f;
    int j = 0;
    for (; j + 4 <= n; j += 4) {
        int4 sv = *reinterpret_cast<const int4*>(el + j);
        if constexpr (SRCPACKED) {
            const uint32* sp = (const uint32*)src;
            uint4 u0 = *reinterpret_cast<const uint4*>(sp + (size_t)sv.x * D + lane * 4);
            uint4 u1 = *reinterpret_cast<const uint4*>(sp + (size_t)sv.y * D + lane * 4);
            uint4 u2 = *reinterpret_cast<const uint4*>(sp + (size_t)sv.z * D + lane * 4);
            uint4 u3 = *reinterpret_cast<const uint4*>(sp + (size_t)sv.w * D + lane * 4);
            a0 += unpack_f32(u0.x) + unpack_f32(u1.x) + unpack_f32(u2.x) + unpack_f32(u3.x);
            a1 += unpack_f32(u0.y) + unpack_f32(u1.y) + unpack_f32(u2.y) + unpack_f32(u3.y);
            a2 += unpack_f32(u0.z) + unpack_f32(u1.z) + unpack_f32(u2.z) + unpack_f32(u3.z);
            a3 += unpack_f32(u0.w) + unpack_f32(u1.w) + unpack_f32(u2.w) + unpack_f32(u3.w);
        } else {
            const float* sp = (const float*)src;
            float4 v0 = *reinterpret_cast<const float4*>(sp + (size_t)sv.x * D + lane * 4);
            float4 v1 = *reinterpret_cast<const float4*>(sp + (size_t)sv.y * D + lane * 4);
            float4 v2 = *reinterpret_cast<const float4*>(sp + (size_t)sv.z * D + lane * 4);
            float4 v3 = *reinterpret_cast<const float4*>(sp + (size_t)sv.w * D + lane * 4);
            a0 += v0.x + v1.x + v2.x + v3.x;
            a1 += v0.y + v1.y + v2.y + v3.y;
            a2 += v0.z + v1.z + v2.z + v3.z;
            a3 += v0.w + v1.w + v2.w + v3.w;
        }
    }
    for (; j < n; ++j) {
        int s = el[j];
        if constexpr (SRCPACKED) {
            uint4 u = *reinterpret_cast<const uint4*>((const uint32*)src + (size_t)s * D + lane * 4);
            a0 += unpack_f32(u.x); a1 += unpack_f32(u.y);
            a2 += unpack_f32(u.z); a3 += unpack_f32(u.w);
        } else {
            float4 v = *reinterpret_cast<const float4*>((const float*)src + (size_t)s * D + lane * 4);
            a0 += v.x; a1 += v.y; a2 += v.z; a3 += v.w;
        }
    }
    float sc = deg > 0 ? 1.0f / (float)deg : 0.0f;
    uint4 o;
    o.x = pack2(a0 * sc); o.y = pack2(a1 * sc);
    o.z = pack2(a2 * sc); o.w = pack2(a3 * sc);
    *reinterpret_cast<uint4*>(aggp + (size_t)t * D + lane * 4) = o;
}

// ---------------------------------------------------------------------------
// Pack W into transposed split form: WTp[n][kc] (kc<256 -> Wl[kc][n], else Wr).
// grid 256 blocks (n), 512 threads (kc).
// ---------------------------------------------------------------------------
__global__ void pack_wt(const float* __restrict__ Wl, const float* __restrict__ Wr,
                        uint32* __restrict__ WTp) {
    int n = blockIdx.x;
    int kc = threadIdx.x;
    float v = (kc < 256) ? Wl[(size_t)kc * D + n] : Wr[(size_t)(kc - 256) * D + n];
    WTp[(size_t)n * 512 + kc] = pack2(v);
}

// ---------------------------------------------------------------------------
// Split-bf16 MFMA GEMM: C[M][256] = act([A1|A2] @ Wcat + bias), K=512.
// 3-term Markidis split per product: hi*hi + hi*lo + lo*hi (fp32 accum).
// 128x128 tile, BK=64, 4 waves (2x2), 4x4 x (16x16x32) fragments per wave.
// LDS XOR-swizzle (byte ^= (row&7)<<4) for conflict-free ds_read_b128.
// ACT 0: relu, store packed u32. ACT 1: tanh, store fp32.
// ---------------------------------------------------------------------------
template<int ACT, bool A2PACKED>
__global__ void __launch_bounds__(256, 2)
gemm_split(const uint32* __restrict__ A1p, const uint32* __restrict__ A2p,
           const float* __restrict__ A2f, const uint32* __restrict__ WTp,
           const float* __restrict__ bias, uint32* __restrict__ Cp,
           float* __restrict__ Cf, int M) {
    __shared__ char sAhi[BM * BKK * 2];
    __shared__ char sAlo[BM * BKK * 2];
    __shared__ char sBhi[BN * BKK * 2];
    __shared__ char sBlo[BN * BKK * 2];

    const int tid = threadIdx.x;
    const int m0 = blockIdx.x * BM;
    const int n0 = blockIdx.y * BN;
    const int wid = tid >> 6, lane = tid & 63;
    const int wm = wid >> 1, wn = wid & 1;
    const int lr = lane & 15;
    const int lk2 = (lane >> 4) * 16;   // byte offset of this lane's k-slice

    f32x4 acc[4][4];
    #pragma unroll
    for (int i = 0; i < 4; ++i)
        #pragma unroll
        for (int j = 0; j < 4; ++j)
            acc[i][j] = (f32x4){0.f, 0.f, 0.f, 0.f};

    for (int k0 = 0; k0 < 512; k0 += BKK) {
        if (k0) __syncthreads();
        // ---- stage A tile: 128 rows x 64 k (source u32/f32), hi/lo bf16 to LDS ----
        #pragma unroll
        for (int it = 0; it < 8; ++it) {
            int flat = it * 1024 + tid * 4;
            int row = flat >> 6;
            int kq = flat & 63;
            int m = m0 + row;
            unsigned short h0, h1, h2, h3, l0, l1, l2, l3;
            if (k0 < 256) {
                uint4 u = make_uint4(0u, 0u, 0u, 0u);
                if (m < M) u = *reinterpret_cast<const uint4*>(A1p + (size_t)m * D + k0 + kq);
                h0 = u.x >> 16; l0 = u.x & 0xffff;
                h1 = u.y >> 16; l1 = u.y & 0xffff;
                h2 = u.z >> 16; l2 = u.z & 0xffff;
                h3 = u.w >> 16; l3 = u.w & 0xffff;
            } else if constexpr (A2PACKED) {
                uint4 u = make_uint4(0u, 0u, 0u, 0u);
                if (m < M) u = *reinterpret_cast<const uint4*>(A2p + (size_t)m * D + (k0 - 256) + kq);
                h0 = u.x >> 16; l0 = u.x & 0xffff;
                h1 = u.y >> 16; l1 = u.y & 0xffff;
                h2 = u.z >> 16; l2 = u.z & 0xffff;
                h3 = u.w >> 16; l3 = u.w & 0xffff;
            } else {
                float4 f = make_float4(0.f, 0.f, 0.f, 0.f);
                if (m < M) f = *reinterpret_cast<const float4*>(A2f + (size_t)m * D + (k0 - 256) + kq);
                h0 = bf16_rne(f.x); l0 = bf16_rne(f.x - bf16_f32(h0));
                h1 = bf16_rne(f.y); l1 = bf16_rne(f.y - bf16_f32(h1));
                h2 = bf16_rne(f.z); l2 = bf16_rne(f.z - bf16_f32(h2));
                h3 = bf16_rne(f.w); l3 = bf16_rne(f.w - bf16_f32(h3));
            }
            int ba = row * (BKK * 2) + ((kq * 2) ^ ((row & 7) << 4));
            *reinterpret_cast<ushort4*>(sAhi + ba) = make_ushort4(h0, h1, h2, h3);
            *reinterpret_cast<ushort4*>(sAlo + ba) = make_ushort4(l0, l1, l2, l3);
        }
        // ---- stage B tile: 128 n-rows x 64 k from WTp (always packed) ----
        #pragma unroll
        for (int it = 0; it < 8; ++it) {
            int flat = it * 1024 + tid * 4;
            int row = flat >> 6;
            int kq = flat & 63;
            uint4 u = *reinterpret_cast<const uint4*>(WTp + (size_t)(n0 + row) * 512 + k0 + kq);
            int bb = row * (BKK * 2) + ((kq * 2) ^ ((row & 7) << 4));
            *reinterpret_cast<ushort4*>(sBhi + bb) =
                make_ushort4(u.x >> 16, u.y >> 16, u.z >> 16, u.w >> 16);
            *reinterpret_cast<ushort4*>(sBlo + bb) =
                make_ushort4(u.x & 0xffff, u.y & 0xffff, u.z & 0xffff, u.w & 0xffff);
        }
        __syncthreads();
        // ---- compute: 2 kk-slabs of K=32 ----
        #pragma unroll
        for (int kk2 = 0; kk2 < BKK * 2; kk2 += 64) {
            short8 ah[4], al[4], bh[4], bl[4];
            #pragma unroll
            for (int f = 0; f < 4; ++f) {
                int ra = wm * 64 + f * 16 + lr;
                int oa = ra * (BKK * 2) + (((kk2 + lk2)) ^ ((ra & 7) << 4));
                ah[f] = *reinterpret_cast<const short8*>(sAhi + oa);
                al[f] = *reinterpret_cast<const short8*>(sAlo + oa);
                int rb = wn * 64 + f * 16 + lr;
                int ob = rb * (BKK * 2) + (((kk2 + lk2)) ^ ((rb & 7) << 4));
                bh[f] = *reinterpret_cast<const short8*>(sBhi + ob);
                bl[f] = *reinterpret_cast<const short8*>(sBlo + ob);
            }
            #pragma unroll
            for (int i = 0; i < 4; ++i)
                #pragma unroll
                for (int j = 0; j < 4; ++j) {
                    acc[i][j] = __builtin_amdgcn_mfma_f32_16x16x32_bf16(ah[i], bh[j], acc[i][j], 0, 0, 0);
                    acc[i][j] = __builtin_amdgcn_mfma_f32_16x16x32_bf16(ah[i], bl[j], acc[i][j], 0, 0, 0);
                    acc[i][j] = __builtin_amdgcn_mfma_f32_16x16x32_bf16(al[i], bh[j], acc[i][j], 0, 0, 0);
                }
        }
    }
    // ---- epilogue: D[row][col], col = lane&15, row = (lane>>4)*4 + reg ----
    #pragma unroll
    for (int fn = 0; fn < 4; ++fn) {
        int col = n0 + wn * 64 + fn * 16 + lr;
        float bv = bias[col];
        #pragma unroll
        for (int fm = 0; fm < 4; ++fm) {
            int rbase = m0 + wm * 64 + fm * 16 + (lane >> 4) * 4;
            #pragma unroll
            for (int r = 0; r < 4; ++r) {
                int m = rbase + r;
                if (m < M) {
                    float v = acc[fm][fn][r] + bv;
                    if (ACT == 0) {
                        v = fmaxf(v, 0.f);
                        Cp[(size_t)m * D + col] = pack2(v);
                    } else {
                        Cf[(size_t)m * D + col] = tanhf(v);
                    }
                }
            }
        }
    }
}

// ---------------------------------------------------------------------------
// Final: out[M][64] = softmax(H @ Wlin + blin).
// One wave per row, NO LDS: Wlin (64 KB) is L2-resident; direct global reads.
// ---------------------------------------------------------------------------
__global__ void final_softmax(const float* __restrict__ H, const float* __restrict__ Wlin,
                              const float* __restrict__ blin, float* __restrict__ out,
                              int M) {
    int wave = threadIdx.x >> 6;
    int lane = threadIdx.x & 63;
    int r = blockIdx.x * 4 + wave;
    if (r >= M) return;

    float4 h = *reinterpret_cast<const float4*>(H + (size_t)r * D + lane * 4);
    float acc = blin[lane];
    #pragma unroll 8
    for (int kq = 0; kq < 64; ++kq) {
        float hx = __shfl(h.x, kq);
        float hy = __shfl(h.y, kq);
        float hz = __shfl(h.z, kq);
        float hw = __shfl(h.w, kq);
        acc += hx * Wlin[(4 * kq + 0) * OUT + lane];
        acc += hy * Wlin[(4 * kq + 1) * OUT + lane];
        acc += hz * Wlin[(4 * kq + 2) * OUT + lane];
        acc += hw * Wlin[(4 * kq + 3) * OUT + lane];
    }
    float mx = acc;
    #pragma unroll
    for (int off = 32; off > 0; off >>= 1) mx = fmaxf(mx, __shfl_xor(mx, off));
    float e = __expf(acc - mx);
    float s = e;
    #pragma unroll
    for (int off = 32; off > 0; off >>= 1) s += __shfl_xor(s, off);
    out[(size_t)r * OUT + lane] = e / s;
}

extern "C" void kernel_launch(void* const* d_in, const int* in_sizes, int n_in,
                              void* d_out, int out_size, void* d_ws, size_t ws_size,
                              hipStream_t stream) {
    const float* x    = (const float*)d_in[0];
    const int*   src0 = (const int*)d_in[1];
    const int*   dst0 = (const int*)d_in[2];
    const int*   src1 = (const int*)d_in[3];
    const int*   dst1 = (const int*)d_in[4];
    const float* Wl0  = (const float*)d_in[5];
    const float* bl0  = (const float*)d_in[6];
    const float* Wr0  = (const float*)d_in[7];
    const float* Wl1  = (const float*)d_in[8];
    const float* bl1  = (const float*)d_in[9];
    const float* Wr1  = (const float*)d_in[10];
    const float* Wlin = (const float*)d_in[11];
    const float* blin = (const float*)d_in[12];

    char* ws = (char*)d_ws;
    size_t off = 0;
    auto alloc = [&](size_t bytes) {
        void* p = ws + off;
        off += (bytes + 255) & ~(size_t)255;
        return p;
    };
    int*    cnt0  = (int*)alloc((size_t)N1 * 4);
    int*    eidx0 = (int*)alloc((size_t)N1 * CAP * 4);
    int*    cnt1  = (int*)alloc((size_t)N2 * 4);
    int*    eidx1 = (int*)alloc((size_t)N2 * CAP * 4);
    uint32* agg0p = (uint32*)alloc((size_t)N1 * D * 4);
    uint32* h0p   = (uint32*)alloc((size_t)N1 * D * 4);
    uint32* agg1p = (uint32*)alloc((size_t)N2 * D * 4);
    float*  h1f   = (float*)alloc((size_t)N2 * D * 4);
    uint32* WTp0  = (uint32*)alloc((size_t)D * 512 * 4);
    uint32* WTp1  = (uint32*)alloc((size_t)D * 512 * 4);

    hipMemsetAsync(cnt0, 0, (size_t)N1 * 4, stream);
    hipMemsetAsync(cnt1, 0, (size_t)N2 * 4, stream);

    pack_wt<<<256, 512, 0, stream>>>(Wl0, Wr0, WTp0);
    pack_wt<<<256, 512, 0, stream>>>(Wl1, Wr1, WTp1);

    fill_edges<<<(E0 + 255) / 256, 256, 0, stream>>>(src0, dst0, cnt0, eidx0, E0);
    aggregate_p<false><<<(N1 + 3) / 4, 256, 0, stream>>>(x, cnt0, eidx0, agg0p, N1);
    gemm_split<0, false><<<dim3((N1 + BM - 1) / BM, 2), 256, 0, stream>>>(
        agg0p, (const uint32*)nullptr, x, WTp0, bl0, h0p, (float*)nullptr, N1);

    fill_edges<<<(E1 + 255) / 256, 256, 0, stream>>>(src1, dst1, cnt1, eidx1, E1);
    aggregate_p<true><<<(N2 + 3) / 4, 256, 0, stream>>>(h0p, cnt1, eidx1, agg1p, N2);
    gemm_split<1, true><<<dim3((N2 + BM - 1) / BM, 2), 256, 0, stream>>>(
        agg1p, h0p, (const float*)nullptr, WTp1, bl1, (uint32*)nullptr, h1f, N2);

    final_softmax<<<(N2 + 3) / 4, 256, 0, stream>>>(h1f, Wlin, blin, (float*)d_out, N2);
}